// Round 13
// baseline (478.674 us; speedup 1.0000x reference)
//
#include <hip/hip_runtime.h>
#include <math.h>

typedef short short8 __attribute__((ext_vector_type(8)));
typedef float float4v __attribute__((ext_vector_type(4)));
#define AS1 __attribute__((address_space(1)))
#define AS3 __attribute__((address_space(3)))

__device__ __forceinline__ float b2f(ushort u) {
    unsigned v = ((unsigned)u) << 16; float f; __builtin_memcpy(&f, &v, 4); return f;
}
__device__ __forceinline__ ushort f2b(float f) {
    unsigned v; __builtin_memcpy(&v, &f, 4);
    unsigned r = (v + 0x7fffu + ((v >> 16) & 1u)) >> 16;
    return (ushort)r;
}

// ---------- merged fp32 -> bf16 convert: all 6 weight/input tensors, ONE launch ----------
// segment decode by block-id range; per-segment zero-pad rows + optional scale.
__global__ void cvt_all(const float* __restrict__ s0, ushort* __restrict__ d0,  // x
                        const float* __restrict__ s1, ushort* __restrict__ d1,  // wq_a
                        const float* __restrict__ s2, ushort* __restrict__ d2,  // wkv_a (pad 576->768)
                        const float* __restrict__ s3, ushort* __restrict__ d3,  // wq_b (scaled)
                        const float* __restrict__ s4, ushort* __restrict__ d4,  // wkv_b
                        const float* __restrict__ s5, ushort* __restrict__ d5,  // wo
                        float scl3) {
    int bid = blockIdx.x;
    const float* src; ushort* dst; int src_rows, cols; float scl = 1.f;
    if (bid < 8192)       {              src = s0; dst = d0; src_rows = 4096; cols = 2048; }
    else if (bid < 11264) { bid -= 8192; src = s1; dst = d1; src_rows = 1536; cols = 2048; }
    else if (bid < 12800) { bid -= 11264; src = s2; dst = d2; src_rows = 576;  cols = 2048; }
    else if (bid < 17408) { bid -= 12800; src = s3; dst = d3; src_rows = 3072; cols = 1536; scl = scl3; }
    else if (bid < 19456) { bid -= 17408; src = s4; dst = d4; src_rows = 4096; cols = 512; }
    else                  { bid -= 19456; src = s5; dst = d5; src_rows = 2048; cols = 2048; }
    size_t e = ((size_t)bid * 256 + threadIdx.x) * 4;
    int r = (int)(e / (size_t)cols);
    ushort4 o;
    if (r < src_rows) {
        float4 v = *(const float4*)(src + e);
        o.x = f2b(v.x * scl); o.y = f2b(v.y * scl); o.z = f2b(v.z * scl); o.w = f2b(v.w * scl);
    } else {
        o.x = 0; o.y = 0; o.z = 0; o.w = 0;
    }
    *(ushort4*)(dst + e) = o;
}

// ---------- 256x256 8-phase bf16 GEMM (T2 swizzle + T3/T4 counted vmcnt + T5) ----------
// C(MxN) = A(MxK) @ B(NxK)^T. M%256==0, N%256==0 (B padded), K%128==0, grid%8==0.
// mode 0: bf16 C (guarded col<ncol); mode 1: f32 C (guarded); mode 2: MLA kv scatter;
// mode 3: bf16 C with FUSED q_pe rope (cols d>=128 of each 192-head; pairs are
//         adjacent lanes -> __shfl_xor(acc,1); rope on f32 before single bf16 round).
__device__ __forceinline__ short8 rdf(const ushort* base, int row, int kb) {
    int raw = row * 128 + kb;
    int off = raw ^ (((raw >> 9) & 1) << 5);
    return *(const short8*)((const char*)base + off);
}
__device__ __forceinline__ void stage_half(const ushort* __restrict__ G, int ldg,
                                           int row0, int k0, ushort* ldsbase,
                                           int wave, int lane) {
#pragma unroll
    for (int rr = 0; rr < 2; ++rr) {
        int x = rr * 8192 + wave * 1024 + lane * 16;   // this thread's linear dst byte
        int l = x ^ (((x >> 9) & 1) << 5);             // logical byte it must hold
        int r = l >> 7, c2 = l & 127;
        __builtin_amdgcn_global_load_lds(
            (const AS1 void*)(G + (size_t)(row0 + r) * ldg + k0 + (c2 >> 1)),
            (AS3 void*)((char*)ldsbase + rr * 8192 + wave * 1024), 16, 0, 0);
    }
}

#define GBAR() do { asm volatile("" ::: "memory"); __builtin_amdgcn_s_barrier(); } while (0)

#define PHASE(QD, SB, VMTAIL, ...) do {                                               \
    short8 a0  = rdf(&sA[SB][0], wm * 128 + (2 * (QD)) * 16 + lq, quad * 16);         \
    short8 a0k = rdf(&sA[SB][0], wm * 128 + (2 * (QD)) * 16 + lq, 64 + quad * 16);    \
    short8 a1  = rdf(&sA[SB][0], wm * 128 + (2 * (QD) + 1) * 16 + lq, quad * 16);     \
    short8 a1k = rdf(&sA[SB][0], wm * 128 + (2 * (QD) + 1) * 16 + lq, 64 + quad * 16);\
    if ((QD) == 0) {                                                                  \
        _Pragma("unroll")                                                             \
        for (int fc = 0; fc < 4; ++fc) {                                              \
            bF[fc][0] = rdf(&sB[SB][0], wn * 64 + fc * 16 + lq, quad * 16);           \
            bF[fc][1] = rdf(&sB[SB][0], wn * 64 + fc * 16 + lq, 64 + quad * 16);      \
        }                                                                             \
    }                                                                                 \
    __VA_ARGS__;                                                                      \
    GBAR();                                                                           \
    __builtin_amdgcn_s_setprio(1);                                                    \
    _Pragma("unroll")                                                                 \
    for (int fc = 0; fc < 4; ++fc) {                                                  \
        acc[2*(QD)][fc]   = __builtin_amdgcn_mfma_f32_16x16x32_bf16(a0,  bF[fc][0], acc[2*(QD)][fc],   0, 0, 0); \
        acc[2*(QD)][fc]   = __builtin_amdgcn_mfma_f32_16x16x32_bf16(a0k, bF[fc][1], acc[2*(QD)][fc],   0, 0, 0); \
        acc[2*(QD)+1][fc] = __builtin_amdgcn_mfma_f32_16x16x32_bf16(a1,  bF[fc][0], acc[2*(QD)+1][fc], 0, 0, 0); \
        acc[2*(QD)+1][fc] = __builtin_amdgcn_mfma_f32_16x16x32_bf16(a1k, bF[fc][1], acc[2*(QD)+1][fc], 0, 0, 0); \
    }                                                                                 \
    __builtin_amdgcn_s_setprio(0);                                                    \
    VMTAIL;                                                                           \
    GBAR();                                                                           \
} while (0)

__global__ __launch_bounds__(512, 2)
void gemm8p(const ushort* __restrict__ A, const ushort* __restrict__ B,
            void* __restrict__ Cv, int K, int lda, int ldb, int ldc, int mode,
            int nbn, int ncol, ushort* __restrict__ Kf, ushort* __restrict__ Vtp,
            const float* __restrict__ freqs) {
    __shared__ ushort sA[2][256 * 64];
    __shared__ ushort sB[2][256 * 64];
    const int tid = threadIdx.x, wave = tid >> 6, lane = tid & 63;
    const int lq = lane & 15, quad = lane >> 4;
    const int wm = wave >> 2, wn = wave & 3;
    const int nwg = gridDim.x;
    const int wg = (blockIdx.x & 7) * (nwg >> 3) + (blockIdx.x >> 3);  // XCD swizzle
    const int bm = (wg / nbn) * 256, bn = (wg % nbn) * 256;

    ushort* sA0h0 = &sA[0][0];     ushort* sA0h1 = &sA[0][8192];
    ushort* sA1h0 = &sA[1][0];     ushort* sA1h1 = &sA[1][8192];
    ushort* sB0h0 = &sB[0][0];     ushort* sB0h1 = &sB[0][8192];
    ushort* sB1h0 = &sB[1][0];     ushort* sB1h1 = &sB[1][8192];

    float4v acc[8][4] = {};
    const int nkt = K >> 6;        // 64-wide K tiles (even; K%128==0)
    const int iters = nkt >> 1;

    // prologue: tile0 (A+B -> buf0), tile1 B -> buf1 (tile1 A staged in iter0 p1,p2)
    stage_half(A, lda, bm,       0, sA0h0, wave, lane);
    stage_half(A, lda, bm + 128, 0, sA0h1, wave, lane);
    stage_half(B, ldb, bn,       0, sB0h0, wave, lane);
    stage_half(B, ldb, bn + 128, 0, sB0h1, wave, lane);
    stage_half(B, ldb, bn,      64, sB1h0, wave, lane);
    stage_half(B, ldb, bn + 128,64, sB1h1, wave, lane);
    asm volatile("s_waitcnt vmcnt(4)" ::: "memory");   // tile0 landed; tile1-B in flight
    GBAR();

    for (int j = 0; j < iters; ++j) {
        const int t1 = 2 * j + 1, t2 = 2 * j + 2, t3 = 2 * j + 3;
        const bool lastj = (j == iters - 1);
        short8 bF[4][2];
        // phases 1-4: tile 2j from buf0
        PHASE(0, 0, (void)0, stage_half(A, lda, bm,       t1 * 64, sA1h0, wave, lane));
        PHASE(1, 0, (void)0, stage_half(A, lda, bm + 128, t1 * 64, sA1h1, wave, lane));
        PHASE(2, 0, (void)0, if (t2 < nkt) stage_half(B, ldb, bn,       t2 * 64, sB0h0, wave, lane));
        PHASE(3, 0,
              if (lastj) { asm volatile("s_waitcnt vmcnt(0)" ::: "memory"); }
              else       { asm volatile("s_waitcnt vmcnt(4)" ::: "memory"); },
              if (t2 < nkt) stage_half(B, ldb, bn + 128, t2 * 64, sB0h1, wave, lane));
        // phases 5-8: tile 2j+1 from buf1
        PHASE(0, 1, (void)0, if (t2 < nkt) stage_half(A, lda, bm,       t2 * 64, sA0h0, wave, lane));
        PHASE(1, 1, (void)0, if (t2 < nkt) stage_half(A, lda, bm + 128, t2 * 64, sA0h1, wave, lane));
        PHASE(2, 1, (void)0, if (t3 < nkt) stage_half(B, ldb, bn,       t3 * 64, sB1h0, wave, lane));
        PHASE(3, 1,
              if (lastj) { asm volatile("s_waitcnt vmcnt(0)" ::: "memory"); }
              else       { asm volatile("s_waitcnt vmcnt(4)" ::: "memory"); },
              if (t3 < nkt) stage_half(B, ldb, bn + 128, t3 * 64, sB1h1, wave, lane));
    }

#pragma unroll
    for (int fr = 0; fr < 8; ++fr) {
        int row0 = bm + wm * 128 + fr * 16 + quad * 4;
#pragma unroll
        for (int fc = 0; fc < 4; ++fc) {
            int col = bn + wn * 64 + fc * 16 + lq;
            if (mode == 0) {
                if (col < ncol) {
                    ushort* C = (ushort*)Cv;
#pragma unroll
                    for (int r = 0; r < 4; ++r)
                        C[(size_t)(row0 + r) * ldc + col] = f2b(acc[fr][fc][r]);
                }
            } else if (mode == 1) {
                if (col < ncol) {
                    float* C = (float*)Cv;
#pragma unroll
                    for (int r = 0; r < 4; ++r)
                        C[(size_t)(row0 + r) * ldc + col] = acc[fr][fc][r];
                }
            } else if (mode == 3) {
                // bf16 store with fused q_pe rope: col = h*192 + d; rope when d >= 128.
                // Pair columns (d, d^1) live in adjacent lanes -> shfl_xor(.,1).
                ushort* C = (ushort*)Cv;
                int d = col % 192;
                bool pe = d >= 128;
                bool odd = (col & 1) != 0;
#pragma unroll
                for (int r = 0; r < 4; ++r) {
                    float v = acc[fr][fc][r];
                    float pr = __shfl_xor(v, 1);   // partner col value (uniform exec)
                    float outv = v;
                    if (pe) {
                        int i2 = (d - 128) >> 1;
                        int s = (row0 + r) & 2047;
                        float cs = freqs[((size_t)s * 32 + i2) * 2];
                        float sn = freqs[((size_t)s * 32 + i2) * 2 + 1];
                        outv = odd ? (pr * sn + v * cs) : (v * cs - pr * sn);
                    }
                    C[(size_t)(row0 + r) * ldc + col] = f2b(outv);
                }
            } else {
                // MLA kv scatter: col = h*256 + c; c<128 -> Kfull nope, else Vt transposed
                int h = col >> 8, c = col & 255;
                int bh = ((row0 >> 11) << 4) + h;
                if (c < 128) {
#pragma unroll
                    for (int r = 0; r < 4; ++r) {
                        int s = (row0 + r) & 2047;
                        Kf[((size_t)bh * 2048 + s) * 200 + c] = f2b(acc[fr][fc][r]);
                    }
                } else {
                    int d = c - 128;
                    int kt = (row0 & 2047) >> 6, kv = row0 & 63;
                    ushort4 o;
                    o.x = f2b(acc[fr][fc][0]); o.y = f2b(acc[fr][fc][1]);
                    o.z = f2b(acc[fr][fc][2]); o.w = f2b(acc[fr][fc][3]);
                    *(ushort4*)(Vtp + (((size_t)bh * 32 + kt) * 128 + d) * 72 + kv) = o;
                }
            }
        }
    }
}

// ---------- fused per-row norm kernel: q rmsnorm + kv rmsnorm + k_pe rope + Kfull fill ----
// one block per row (4096). Replaces rmsnorm_inplace + kvnorm_rope + kpe_fill (3 launches).
__global__ void norm_fused(ushort* __restrict__ qakv, const float* __restrict__ qnw,
                           const float* __restrict__ kvnw, const float* __restrict__ freqs,
                           ushort* __restrict__ kvc, ushort* __restrict__ Kfull) {
    const int row = blockIdx.x, tid = threadIdx.x;
    const int s = row & 2047, b = row >> 11;
    __shared__ float red[4];
    __shared__ ushort kvpe[64];
    // --- phase 1: rmsnorm in-place on qakv[row][0..1535] (ld 2176) ---
    ushort* p = qakv + (size_t)row * 2176;
    float ss = 0.f;
    for (int i = tid; i < 1536; i += 256) { float v = b2f(p[i]); ss += v * v; }
#pragma unroll
    for (int off = 32; off >= 1; off >>= 1) ss += __shfl_xor(ss, off);
    if ((tid & 63) == 0) red[tid >> 6] = ss;
    __syncthreads();
    float rs = rsqrtf((red[0] + red[1] + red[2] + red[3]) / 1536.f + 1e-6f);
    for (int i = tid; i < 1536; i += 256) p[i] = f2b(b2f(p[i]) * rs * qnw[i]);
    __syncthreads();   // all reads of red done before reuse
    // --- phase 2: kv rmsnorm on cols 1536..2047 -> kvc; rope cols 2048..2111 ---
    const ushort* pk = p + 1536;
    float v0 = b2f(pk[tid]), v1 = b2f(pk[tid + 256]);
    float s2 = v0 * v0 + v1 * v1;
#pragma unroll
    for (int off = 32; off >= 1; off >>= 1) s2 += __shfl_xor(s2, off);
    if ((tid & 63) == 0) red[tid >> 6] = s2;
    __syncthreads();
    float rs2 = rsqrtf((red[0] + red[1] + red[2] + red[3]) / 512.f + 1e-6f);
    kvc[(size_t)row * 512 + tid] = f2b(v0 * rs2 * kvnw[tid]);
    kvc[(size_t)row * 512 + tid + 256] = f2b(v1 * rs2 * kvnw[tid + 256]);
    if (tid < 32) {
        float re = b2f(pk[512 + 2 * tid]), im = b2f(pk[512 + 2 * tid + 1]);
        float cs = freqs[(s * 32 + tid) * 2], sn = freqs[(s * 32 + tid) * 2 + 1];
        kvpe[2 * tid]     = f2b(re * cs - im * sn);
        kvpe[2 * tid + 1] = f2b(re * sn + im * cs);
    }
    __syncthreads();
    // --- phase 3: broadcast roped k_pe into Kfull[(b*16+h)][s][128..191], h=0..15 ---
    int h = tid >> 4, c4 = (tid & 15) * 4;
    ushort4 v;
    v.x = kvpe[c4]; v.y = kvpe[c4 + 1]; v.z = kvpe[c4 + 2]; v.w = kvpe[c4 + 3];
    *(ushort4*)(Kfull + ((size_t)(b * 16 + h) * 2048 + s) * 200 + 128 + c4) = v;
}

// ---------- causal flash attention: R6 schedule, KVBLK=128 (proven 104us, R11/R12) ----------
__global__ __launch_bounds__(512, 2)
void mla_attn13(const ushort* __restrict__ q, const ushort* __restrict__ Kfull,
                const ushort* __restrict__ Vt, ushort* __restrict__ out) {
    __shared__ ushort sK[128 * 200];
    __shared__ ushort sP[8][16][72];
    const int tid = threadIdx.x, wave = tid >> 6, lane = tid & 63;
    const int lq = lane & 15, quad = lane >> 4;
    const int lin = blockIdx.x;
    const int e = lin & 7, idx = lin >> 3;
    const int st = 15 - (idx >> 2);          // 128-row q super-tile, big first
    const int bh = e + 8 * (idx & 3);        // XCD-pinned: bh%8 == lin%8
    const int b = bh >> 4, h = bh & 15;
    const ushort* Kb = Kfull + (size_t)bh * 2048 * 200;
    const ushort* Vb = Vt + (size_t)bh * 32 * 128 * 72;

    const int qrow = st * 128 + wave * 16 + lq;
    const ushort* qp = q + ((size_t)(b * 2048 + qrow) * 16 + h) * 192 + quad * 8;
    short8 qf[6];
#pragma unroll
    for (int c = 0; c < 6; ++c) qf[c] = *(const short8*)(qp + c * 32);

    float4v oacc[8] = {};
    float m_i[4] = {-INFINITY, -INFINITY, -INFINITY, -INFINITY};
    float l_i[4] = {0.f, 0.f, 0.f, 0.f};
    const int myrow0 = st * 128 + wave * 16 + quad * 4;

    for (int kt = 0; kt <= st; ++kt) {
        // stage 128x200 K tile (3200 16B-chunks) across all 512 threads
        const ushort* Ksrc = Kb + (size_t)kt * 128 * 200;
#pragma unroll
        for (int i = 0; i < 7; ++i) {
            int cb = i * 512 + wave * 64;    // wave-uniform chunk base
            if (cb < 3200)
                __builtin_amdgcn_global_load_lds((const AS1 void*)(Ksrc + (size_t)(cb + lane) * 8),
                                                 (AS3 void*)(sK + cb * 8), 16, 0, 0);
        }
        __syncthreads();
        // V subtiles for this 128-kv tile (Vt is stored in 64-kv units)
        const ushort* Vs0 = Vb + (size_t)(2 * kt) * 128 * 72 + (size_t)lq * 72 + quad * 8;
        const ushort* Vs1 = Vs0 + 128 * 72;
        // S = Q K^T (per wave: 16 x 128)
        float4v sc[8];
#pragma unroll
        for (int ct = 0; ct < 8; ++ct) {
            float4v a = {0.f, 0.f, 0.f, 0.f};
#pragma unroll
            for (int c = 0; c < 6; ++c) {
                short8 kf = *(const short8*)(sK + (ct * 16 + lq) * 200 + c * 32 + quad * 8);
                a = __builtin_amdgcn_mfma_f32_16x16x32_bf16(qf[c], kf, a, 0, 0, 0);
            }
            sc[ct] = a;
        }
        // hoist V loads for half0/kc0 from L2: independent, fly during softmax
        short8 vf00[8];
#pragma unroll
        for (int dt = 0; dt < 8; ++dt)
            vf00[dt] = *(const short8*)(Vs0 + (size_t)dt * 16 * 72);
        // causal mask (branchless; only the diagonal tile actually masks) + max
        float mnew[4];
#pragma unroll
        for (int r = 0; r < 4; ++r) mnew[r] = m_i[r];
#pragma unroll
        for (int ct = 0; ct < 8; ++ct)
#pragma unroll
            for (int r = 0; r < 4; ++r) {
                float v = (kt * 128 + ct * 16 + lq) > (myrow0 + r) ? -INFINITY : sc[ct][r];
                sc[ct][r] = v;
                mnew[r] = fmaxf(mnew[r], v);
            }
#pragma unroll
        for (int off = 8; off >= 1; off >>= 1)
#pragma unroll
            for (int r = 0; r < 4; ++r) mnew[r] = fmaxf(mnew[r], __shfl_xor(mnew[r], off));
        // defer-max: rescale only if the max grew by > 8 (log2 domain)
        float g = mnew[0] - m_i[0];
#pragma unroll
        for (int r = 1; r < 4; ++r) g = fmaxf(g, mnew[r] - m_i[r]);
        if (__ballot(g > 8.0f) != 0ull) {
#pragma unroll
            for (int r = 0; r < 4; ++r) {
                float a = __builtin_amdgcn_exp2f(m_i[r] - mnew[r]);
                m_i[r] = mnew[r];
                l_i[r] *= a;
#pragma unroll
                for (int dt = 0; dt < 8; ++dt) oacc[dt][r] *= a;
            }
        }
        float psum[4] = {0.f, 0.f, 0.f, 0.f};
        // ---- half 0: P columns 0..63 ----
#pragma unroll
        for (int c4 = 0; c4 < 4; ++c4)
#pragma unroll
            for (int r = 0; r < 4; ++r) {
                float pv = __builtin_amdgcn_exp2f(sc[c4][r] - m_i[r]);
                psum[r] += pv;
                sP[wave][quad * 4 + r][c4 * 16 + lq] = f2b(pv);
            }
#pragma unroll
        for (int kc = 0; kc < 2; ++kc) {
            short8 pf = *(const short8*)(&sP[wave][lq][kc * 32 + quad * 8]);
#pragma unroll
            for (int dt = 0; dt < 8; ++dt) {
                short8 vf = kc == 0 ? vf00[dt]
                                    : *(const short8*)(Vs0 + (size_t)dt * 16 * 72 + 32);
                oacc[dt] = __builtin_amdgcn_mfma_f32_16x16x32_bf16(pf, vf, oacc[dt], 0, 0, 0);
            }
        }
        // ---- half 1: P columns 64..127 (sP reuse: same-wave DS order is safe) ----
#pragma unroll
        for (int c4 = 0; c4 < 4; ++c4)
#pragma unroll
            for (int r = 0; r < 4; ++r) {
                float pv = __builtin_amdgcn_exp2f(sc[4 + c4][r] - m_i[r]);
                psum[r] += pv;
                sP[wave][quad * 4 + r][c4 * 16 + lq] = f2b(pv);
            }
#pragma unroll
        for (int kc = 0; kc < 2; ++kc) {
            short8 pf = *(const short8*)(&sP[wave][lq][kc * 32 + quad * 8]);
#pragma unroll
            for (int dt = 0; dt < 8; ++dt) {
                short8 vf = *(const short8*)(Vs1 + (size_t)dt * 16 * 72 + kc * 32);
                oacc[dt] = __builtin_amdgcn_mfma_f32_16x16x32_bf16(pf, vf, oacc[dt], 0, 0, 0);
            }
        }
        // one shuffle-reduce per 128 kv (was per 64)
#pragma unroll
        for (int off = 8; off >= 1; off >>= 1)
#pragma unroll
            for (int r = 0; r < 4; ++r) psum[r] += __shfl_xor(psum[r], off);
#pragma unroll
        for (int r = 0; r < 4; ++r) l_i[r] += psum[r];
        __syncthreads();   // protect sK before next stage
    }
    float inv[4];
#pragma unroll
    for (int r = 0; r < 4; ++r) inv[r] = 1.f / l_i[r];
#pragma unroll
    for (int dt = 0; dt < 8; ++dt) {
#pragma unroll
        for (int r = 0; r < 4; ++r) {
            out[((size_t)(b * 2048 + myrow0 + r) * 16 + h) * 128 + dt * 16 + lq] =
                f2b(oacc[dt][r] * inv[r]);
        }
    }
}

// ---------- launch (7 dispatches, was 15) ----------
extern "C" void kernel_launch(void* const* d_in, const int* in_sizes, int n_in,
                              void* d_out, int out_size, void* d_ws, size_t ws_size,
                              hipStream_t stream) {
    const float* x     = (const float*)d_in[0];
    const float* freqs = (const float*)d_in[2];
    const float* wq_a  = (const float*)d_in[3];
    const float* qnw   = (const float*)d_in[4];
    const float* wq_b  = (const float*)d_in[5];
    const float* wkv_a = (const float*)d_in[6];
    const float* kvnw  = (const float*)d_in[7];
    const float* wkv_b = (const float*)d_in[8];
    const float* wo    = (const float*)d_in[9];

    char* ws = (char*)d_ws;
    size_t off = 0;
    auto alloc = [&](size_t n) { char* p = ws + off; off += (n + 255) & ~(size_t)255; return p; };
    ushort* xb    = (ushort*)alloc(4096ull * 2048 * 2);   // dead after fused a-gemm
    ushort* wqkva = (ushort*)alloc(2304ull * 2048 * 2);   // 2304 rows (N-pad to 9x256); dead after a-gemm
    ushort* wqbb  = (ushort*)alloc(3072ull * 1536 * 2);   // dead after q_b gemm
    ushort* wkvbb = (ushort*)alloc(4096ull * 512 * 2);    // live until kv_b gemm
    ushort* wob   = (ushort*)alloc(2048ull * 2048 * 2);   // live until final gemm
    ushort* qakv  = (ushort*)alloc(4096ull * 2176 * 2);   // dead after q_b gemm
    ushort* kvc   = (ushort*)alloc(4096ull * 512 * 2);    // live until kv_b gemm
    ushort* kpe   = (ushort*)alloc(4096ull * 64 * 2);     // unused (kept for layout stability)
    ushort* qfull = (ushort*)alloc(4096ull * 3072 * 2);
    ushort* kvbuf = (ushort*)alloc(4096ull * 4096 * 2);   // hosts Kfull (26.2 <= 33.6 MB)
    ushort* attno = (ushort*)alloc(4096ull * 2048 * 2);
    if (off > ws_size) return;
    (void)kpe;
    ushort* Kfull = kvbuf;
    ushort* Vt = xb;   // Vt (18.9MB) over xb+wqkva (26.2MB), both dead before kv_b gemm

    const float qk_scale = 1.44269504f / sqrtf(192.0f);
    // 1) all fp32->bf16 conversions in one launch (23552 blocks; see cvt_all decode)
    cvt_all<<<dim3(23552), 256, 0, stream>>>(x, xb, wq_a, wqkva,
                                             wkv_a, wqkva + 1536ull * 2048,
                                             wq_b, wqbb, wkv_b, wkvbb, wo, wob, qk_scale);
    // 2) fused q_a + kv_a projection: 4096 x (2176 of 2304) x 2048, 8-phase, 144 blocks
    gemm8p<<<dim3(144), 512, 0, stream>>>(xb, wqkva, qakv, 2048, 2048, 2048, 2176, 0, 9, 2176, nullptr, nullptr, nullptr);
    // 3) fused norms + k_pe rope + Kfull pe-fill
    norm_fused<<<dim3(4096), 256, 0, stream>>>(qakv, qnw, kvnw, freqs, kvc, Kfull);
    // 4) q_b projection with FUSED q_pe rope: 4096x3072x1536, 8-phase, 192 blocks
    gemm8p<<<dim3(192), 512, 0, stream>>>(qakv, wqbb, qfull, 1536, 2176, 1536, 3072, 3, 12, 3072, nullptr, nullptr, freqs);
    // 5) kv_b gemm with fused scatter epilogue: 4096x4096x512, 8-phase, 256 blocks
    gemm8p<<<dim3(256), 512, 0, stream>>>(kvc, wkvbb, nullptr, 512, 512, 512, 0, 2, 16, 0, Kfull, Vt, nullptr);
    // 6) attention
    mla_attn13<<<dim3(512), 512, 0, stream>>>(qfull, Kfull, Vt, attno);
    // 7) out projection: 4096x2048x2048 f32, 8-phase, 128 blocks
    gemm8p<<<dim3(128), 512, 0, stream>>>(attno, wob, (float*)d_out, 2048, 2048, 2048, 2048, 1, 8, 2048, nullptr, nullptr, nullptr);
}